// Round 1
// 293.060 us; speedup vs baseline: 1.0304x; 1.0304x over previous
//
#include <hip/hip_runtime.h>
#include <hip/hip_bf16.h>
#include <stdint.h>

#define M_DIM 4096
#define N_DIM 10000
#define K_DIM 1024
#define GM (M_DIM / 256)            // 16 row-tiles
#define GN ((N_DIM + 255) / 256)    // 40 col-tiles (last covers 9984..10239, stores predicated)
#define NT (K_DIM / 32)             // 32 K-tiles of BK=32

typedef __attribute__((ext_vector_type(8))) short bf16x8;
typedef __attribute__((ext_vector_type(4))) float f32x4;

#define BAR()      asm volatile("s_barrier" ::: "memory")
#define WAITVM4()  asm volatile("s_waitcnt vmcnt(4)" ::: "memory")
#define WAITVM0()  asm volatile("s_waitcnt vmcnt(0)" ::: "memory")
#define WAITLGKM() asm volatile("s_waitcnt lgkmcnt(0)" ::: "memory")

// async global->LDS, 16B per lane. LDS dest must be wave-uniform base + lane*16.
__device__ __forceinline__ void async_ld16(const void* g, void* l) {
    __builtin_amdgcn_global_load_lds(
        (const __attribute__((address_space(1))) unsigned int*)g,
        (__attribute__((address_space(3))) unsigned int*)l,
        16, 0, 0);
}

__device__ __forceinline__ unsigned short f2bf(float f) {
    unsigned u = __float_as_uint(f);
    unsigned r = (u + 0x7FFFu + ((u >> 16) & 1u)) >> 16;  // RNE
    return (unsigned short)r;
}

// Wave-per-row: fp32 -> bf16 convert + exact fp32 ||x||^2. Grid-stride over
// the 14096 rows (feat then centers). 1024 floats/row = 64 lanes x 4 float4.
__global__ __launch_bounds__(256) void prep_rows(
    const float* __restrict__ feat, const float* __restrict__ cent,
    unsigned short* __restrict__ featbf, unsigned short* __restrict__ centbf,
    float* __restrict__ fsq, float* __restrict__ csq)
{
    const int wlane = threadIdx.x & 63;
    const int wid   = blockIdx.x * 4 + (threadIdx.x >> 6);
    const int nw    = gridDim.x * 4;
    for (int row = wid; row < M_DIM + N_DIM; row += nw) {
        const float* in;
        unsigned short* outb;
        float* sqp;
        if (row < M_DIM) {
            in = feat + (size_t)row * K_DIM;
            outb = featbf + (size_t)row * K_DIM;
            sqp = fsq + row;
        } else {
            const int r2 = row - M_DIM;
            in = cent + (size_t)r2 * K_DIM;
            outb = centbf + (size_t)r2 * K_DIM;
            sqp = csq + r2;
        }
        float s = 0.f;
        #pragma unroll
        for (int c = 0; c < 4; c++) {
            float4 v = ((const float4*)in)[wlane + c * 64];
            ushort4 pk;
            pk.x = f2bf(v.x); pk.y = f2bf(v.y); pk.z = f2bf(v.z); pk.w = f2bf(v.w);
            ((ushort4*)outb)[wlane + c * 64] = pk;
            s += v.x * v.x + v.y * v.y + v.z * v.z + v.w * v.w;
        }
        #pragma unroll
        for (int off = 32; off > 0; off >>= 1) s += __shfl_down(s, off, 64);
        if (wlane == 0) *sqp = s;
    }
}

// C[m][n] = sum_k A[m][k]*B[n][k] (both K-major), epilogue adds norms.
//
// 256x256 tile, BK=32, 8 waves (2M x 4N), each wave owns 128x64 (8x4 frags of
// mfma 16x16x32 bf16). Phase-split schedule (T3+T4): triple-buffered LDS
// (3 x 32KB), staging runs TWO K-tiles ahead -> the counted vmcnt(4) at each
// tile boundary leaves only tile t+2's 4 loads in flight; the buffer being
// read is never a staging target, so no drain-to-0 in the main loop.
// Per phase: {ds_read frags | issue 2 global_load_lds | barrier | lgkmcnt(0) |
// setprio(1) 16 MFMA setprio(0) | barrier}.
//
// T2 swizzle: ds_read_b128 at 64B row stride is 8-way bank-conflicted; reads
// XOR the 16B-slot index with row bits [2:1] (2-way = free). global_load_lds
// writes LDS linearly, so the same XOR is pre-applied to the per-lane GLOBAL
// k-offset at staging (involution: linear dest + inv-swz source + swz read).
__global__ __launch_bounds__(512, 2) void gemm_bt(
    const unsigned short* __restrict__ A,   // featbf [M][K]
    const unsigned short* __restrict__ B,   // centbf [N][K]
    const float* __restrict__ fsq, const float* __restrict__ csq,
    float* __restrict__ out)
{
    // 3 buffers x (A 256x32 @ 0..16KB, B 256x32 @ 16..32KB) = 96 KB
    __shared__ unsigned short smem[49152];

    const int tid  = threadIdx.x;
    const int lane = tid & 63;
    const int wave = tid >> 6;            // 0..7
    const int wm = wave & 1;              // 2 M-warps x 128 rows
    const int wn = wave >> 1;             // 4 N-warps x 64 cols
    const int mlane = lane & 15;
    const int quad  = lane >> 4;
    const int fr  = (mlane >> 1) & 3;             // row bits [2:1] (row = C16 + mlane)
    const int qx  = (quad ^ fr) << 4;             // swizzled 16B slot

    // T1: bijective XCD swizzle (640 % 8 == 0). Each XCD gets bn in
    // [xcd*5, xcd*5+5) across all bm -> B panels served from one L2.
    const int bid = blockIdx.x;
    const int xcd = bid & 7;
    const int idx = bid >> 3;                     // 0..79
    const int r0  = xcd * 80 + idx;
    const int bm  = r0 & 15;
    const int bn  = r0 >> 4;

    const int arow_base = bm * 256;
    const int brow_base = bn * 256;

    // staging precompute: 4 loads/thread/K-tile (A0,A1,B0,B1), slot = i*512+tid,
    // LDS byte = slot*16 (linear; wave-uniform base + lane*16 holds), global
    // k-offset pre-swizzled: k = (slot%4 ^ ((row>>1)&3)) * 8 shorts.
    const unsigned short* gA[2];
    const unsigned short* gB[2];
    int ldsA[2], ldsB[2];
    #pragma unroll
    for (int i = 0; i < 2; i++) {
        const int s   = i * 512 + tid;            // 0..1023
        const int row = s >> 2;                   // 0..255
        const int sc  = s & 3;
        const int kof = (sc ^ ((row >> 1) & 3)) << 3;
        gA[i] = A + (size_t)(arow_base + row) * K_DIM + kof;
        int br = brow_base + row; if (br > N_DIM - 1) br = N_DIM - 1;
        gB[i] = B + (size_t)br * K_DIM + kof;
        ldsA[i] = s * 16;
        ldsB[i] = 16384 + s * 16;
    }

    #define STAGE_A(t2, nbb)                                                  \
        do {                                                                  \
            async_ld16(gA[0] + (size_t)(t2) * 32, (char*)smem + (nbb) + ldsA[0]); \
            async_ld16(gA[1] + (size_t)(t2) * 32, (char*)smem + (nbb) + ldsA[1]); \
        } while (0)
    #define STAGE_B(t2, nbb)                                                  \
        do {                                                                  \
            async_ld16(gB[0] + (size_t)(t2) * 32, (char*)smem + (nbb) + ldsB[0]); \
            async_ld16(gB[1] + (size_t)(t2) * 32, (char*)smem + (nbb) + ldsB[1]); \
        } while (0)

    f32x4 acc[8][4];
    #pragma unroll
    for (int i = 0; i < 8; i++)
        #pragma unroll
        for (int j = 0; j < 4; j++) {
            f32x4 z = {0.f, 0.f, 0.f, 0.f};
            acc[i][j] = z;
        }

    // ds_read bases (bytes within a buffer); frag (mh,i): +mh*4096 + i*1024
    const int aBase = (wm * 128 + mlane) * 64 + qx;
    const int bBase = 16384 + (wn * 64 + mlane) * 64 + qx;

    // prologue: tiles 0 and 1; vmcnt(4) -> tile 0 landed, tile 1 in flight
    STAGE_A(0, 0); STAGE_B(0, 0);
    STAGE_A(1, 32768); STAGE_B(1, 32768);
    WAITVM4();
    BAR();

    int bb = 0;                                   // buffer byte base of tile t
    for (int t = 0; t < NT; ++t) {
        int nb = bb - 32768; if (nb < 0) nb = 65536;   // buffer of tile t+2
        const char* base = (const char*)smem + bb;
        bf16x8 af[4], bfv[4];

        // ---- phase 0: A rows mh=0 + all B cols; stage A of tile t+2 ----
        #pragma unroll
        for (int i = 0; i < 4; i++) {
            af[i]  = *(const bf16x8*)(base + aBase + i * 1024);
            bfv[i] = *(const bf16x8*)(base + bBase + i * 1024);
        }
        if (t + 2 < NT) STAGE_A(t + 2, nb);
        BAR();
        WAITLGKM();
        __builtin_amdgcn_s_setprio(1);
        #pragma unroll
        for (int i = 0; i < 4; i++)
            #pragma unroll
            for (int j = 0; j < 4; j++)
                acc[i][j] = __builtin_amdgcn_mfma_f32_16x16x32_bf16(
                    af[i], bfv[j], acc[i][j], 0, 0, 0);
        __builtin_amdgcn_s_setprio(0);
        BAR();

        // ---- phase 1: A rows mh=1 (B frags reused); stage B of tile t+2 ----
        #pragma unroll
        for (int i = 0; i < 4; i++)
            af[i] = *(const bf16x8*)(base + aBase + 4096 + i * 1024);
        if (t + 2 < NT) STAGE_B(t + 2, nb);
        BAR();
        WAITLGKM();
        __builtin_amdgcn_s_setprio(1);
        #pragma unroll
        for (int i = 0; i < 4; i++)
            #pragma unroll
            for (int j = 0; j < 4; j++)
                acc[4 + i][j] = __builtin_amdgcn_mfma_f32_16x16x32_bf16(
                    af[i], bfv[j], acc[4 + i][j], 0, 0, 0);
        __builtin_amdgcn_s_setprio(0);

        // boundary: tile t+1 must be landed; tile t+2's 4 loads stay in flight
        if (t < NT - 1) {
            if (t + 2 < NT) { WAITVM4(); } else { WAITVM0(); }
        }
        BAR();

        bb += 32768; if (bb > 65536) bb = 0;
    }
    #undef STAGE_A
    #undef STAGE_B

    // epilogue: fold norms, transpose 16x64 chunks through LDS, NT f32x4
    // stores (256B contiguous per row segment). Per-wave scratch 16 x stride-68.
    float* W = (float*)smem + wave * 1088;        // 8 waves x 1088 f32 = 34.8 KB
    const int rbase0 = arow_base + wm * 128;
    const int cbase  = brow_base + wn * 64 + mlane;
    const int rb_col4 = mlane * 4;
    const int gcol4  = brow_base + wn * 64 + rb_col4;
    const bool colok = gcol4 < N_DIM;             // 4-aligned, N%4==0 -> +3 safe

    #pragma unroll
    for (int i = 0; i < 8; i++) {
        float frow[4];
        #pragma unroll
        for (int r = 0; r < 4; r++)
            frow[r] = -0.5f * fsq[rbase0 + i * 16 + quad * 4 + r];
        #pragma unroll
        for (int j = 0; j < 4; j++) {
            int col = cbase + j * 16;
            float cs = -0.5f * csq[col < N_DIM ? col : (N_DIM - 1)];
            #pragma unroll
            for (int r = 0; r < 4; r++)
                W[(quad * 4 + r) * 68 + j * 16 + mlane] = acc[i][j][r] + frow[r] + cs;
        }
        WAITLGKM();  // writes visible to own-wave reads
        #pragma unroll
        for (int s = 0; s < 4; s++) {
            int rl = s * 4 + quad;
            f32x4 v = *(const f32x4*)&W[rl * 68 + rb_col4];
            if (colok) {
                int grow = rbase0 + i * 16 + rl;
                __builtin_nontemporal_store(v, (f32x4*)&out[(size_t)grow * N_DIM + gcol4]);
            }
        }
        WAITLGKM();  // reads done before next i overwrites W
    }
}

extern "C" void kernel_launch(void* const* d_in, const int* in_sizes, int n_in,
                              void* d_out, int out_size, void* d_ws, size_t ws_size,
                              hipStream_t stream) {
    const float* feat = (const float*)d_in[0];   // [4096,1024]
    const float* cent = (const float*)d_in[1];   // [10000,1024]
    float* out = (float*)d_out;                  // [4096,10000]

    char* ws = (char*)d_ws;
    unsigned short* featbf = (unsigned short*)ws;                         // 8,388,608 B
    unsigned short* centbf = (unsigned short*)(ws + 8388608);             // 20,480,000 B
    float* fsq = (float*)(ws + 8388608 + 20480000);                       // 16,384 B
    float* csq = (float*)(ws + 8388608 + 20480000 + 16384);               // 40,000 B

    prep_rows<<<1024, 256, 0, stream>>>(feat, cent, featbf, centbf, fsq, csq);

    gemm_bt<<<GM * GN, 512, 0, stream>>>(featbf, centbf, fsq, csq, out);
}

// Round 2
// 287.937 us; speedup vs baseline: 1.0487x; 1.0178x over previous
//
#include <hip/hip_runtime.h>
#include <hip/hip_bf16.h>
#include <stdint.h>

#define M_DIM 4096
#define N_DIM 10000
#define K_DIM 1024
#define GM (M_DIM / 256)            // 16 row-tiles
#define GN ((N_DIM + 255) / 256)    // 40 col-tiles (last covers 9984..10239, stores predicated)
#define NT (K_DIM / 32)             // 32 K-tiles of BK=32

typedef __attribute__((ext_vector_type(8))) short bf16x8;
typedef __attribute__((ext_vector_type(4))) float f32x4;

#define BAR()      asm volatile("s_barrier" ::: "memory")
#define WAITVM8()  asm volatile("s_waitcnt vmcnt(8)" ::: "memory")
#define WAITVM4()  asm volatile("s_waitcnt vmcnt(4)" ::: "memory")
#define WAITVM0()  asm volatile("s_waitcnt vmcnt(0)" ::: "memory")
#define WAITLGKM() asm volatile("s_waitcnt lgkmcnt(0)" ::: "memory")

// async global->LDS, 16B per lane. LDS dest must be wave-uniform base + lane*16.
__device__ __forceinline__ void async_ld16(const void* g, void* l) {
    __builtin_amdgcn_global_load_lds(
        (const __attribute__((address_space(1))) unsigned int*)g,
        (__attribute__((address_space(3))) unsigned int*)l,
        16, 0, 0);
}

__device__ __forceinline__ unsigned short f2bf(float f) {
    unsigned u = __float_as_uint(f);
    unsigned r = (u + 0x7FFFu + ((u >> 16) & 1u)) >> 16;  // RNE
    return (unsigned short)r;
}

// Wave-per-row: fp32 -> bf16 convert + exact fp32 ||x||^2. Grid-stride over
// the 14096 rows (feat then centers). 1024 floats/row = 64 lanes x 4 float4.
__global__ __launch_bounds__(256) void prep_rows(
    const float* __restrict__ feat, const float* __restrict__ cent,
    unsigned short* __restrict__ featbf, unsigned short* __restrict__ centbf,
    float* __restrict__ fsq, float* __restrict__ csq)
{
    const int wlane = threadIdx.x & 63;
    const int wid   = blockIdx.x * 4 + (threadIdx.x >> 6);
    const int nw    = gridDim.x * 4;
    for (int row = wid; row < M_DIM + N_DIM; row += nw) {
        const float* in;
        unsigned short* outb;
        float* sqp;
        if (row < M_DIM) {
            in = feat + (size_t)row * K_DIM;
            outb = featbf + (size_t)row * K_DIM;
            sqp = fsq + row;
        } else {
            const int r2 = row - M_DIM;
            in = cent + (size_t)r2 * K_DIM;
            outb = centbf + (size_t)r2 * K_DIM;
            sqp = csq + r2;
        }
        float s = 0.f;
        #pragma unroll
        for (int c = 0; c < 4; c++) {
            float4 v = ((const float4*)in)[wlane + c * 64];
            ushort4 pk;
            pk.x = f2bf(v.x); pk.y = f2bf(v.y); pk.z = f2bf(v.z); pk.w = f2bf(v.w);
            ((ushort4*)outb)[wlane + c * 64] = pk;
            s += v.x * v.x + v.y * v.y + v.z * v.z + v.w * v.w;
        }
        #pragma unroll
        for (int off = 32; off > 0; off >>= 1) s += __shfl_down(s, off, 64);
        if (wlane == 0) *sqp = s;
    }
}

// C[m][n] = sum_k A[m][k]*B[n][k] (both K-major), epilogue adds norms.
//
// 256x256 tile, BK=32, 8 waves (2M x 4N), each wave owns 128x64 (8x4 frags of
// mfma 16x16x32 bf16).
//
// Schedule (rev 2): QUAD-buffered LDS (4 x 32KB), staging runs THREE K-tiles
// ahead -> boundary wait is a counted vmcnt(8) (tiles t+2,t+3 in flight; t+1
// guaranteed resident). TWO raw barriers per tile:
//   region A: {ds_read mh=0 frags + B frags | stage A(t+3) | 16 MFMA}
//   BAR  (mid-tile align; no data hazard -- scheduling only)
//   region B: {ds_read mh=1 frags | stage B(t+3) | 16 MFMA | vmcnt(8)}
//   BAR  (boundary: buffer t+1 complete for ALL waves' loads)
// No forced lgkmcnt(0): reads are compiler-visible, so counted lgkm waits let
// the first MFMA start as soon as its two operands land; waves drift within a
// region so one wave's ds_reads run under its SIMD-sibling's MFMA cluster.
// Hazard proof: stage of tile t+3 (issued in tile t) writes buffer (t+3)&3 =
// (t-1)&3, whose last reader finished before tile t-1's boundary barrier.
//
// T2 swizzle: ds_read_b128 at 64B row stride is 8-way bank-conflicted; reads
// XOR the 16B-slot index with row bits [2:1] (2-way = free). global_load_lds
// writes LDS linearly, so the same XOR is pre-applied to the per-lane GLOBAL
// k-offset at staging (involution: linear dest + inv-swz source + swz read).
__global__ __launch_bounds__(512, 2) void gemm_bt(
    const unsigned short* __restrict__ A,   // featbf [M][K]
    const unsigned short* __restrict__ B,   // centbf [N][K]
    const float* __restrict__ fsq, const float* __restrict__ csq,
    float* __restrict__ out)
{
    // 4 buffers x (A 256x32 @ 0..16KB, B 256x32 @ 16..32KB) = 128 KB
    __shared__ unsigned short smem[65536];

    const int tid  = threadIdx.x;
    const int lane = tid & 63;
    const int wave = tid >> 6;            // 0..7
    const int wm = wave & 1;              // 2 M-warps x 128 rows
    const int wn = wave >> 1;             // 4 N-warps x 64 cols
    const int mlane = lane & 15;
    const int quad  = lane >> 4;
    const int fr  = (mlane >> 1) & 3;             // row bits [2:1] (row = C16 + mlane)
    const int qx  = (quad ^ fr) << 4;             // swizzled 16B slot

    // T1: bijective XCD swizzle (640 % 8 == 0). Each XCD gets bn in
    // [xcd*5, xcd*5+5) across all bm -> B panels served from one L2.
    const int bid = blockIdx.x;
    const int xcd = bid & 7;
    const int idx = bid >> 3;                     // 0..79
    const int r0  = xcd * 80 + idx;
    const int bm  = r0 & 15;
    const int bn  = r0 >> 4;

    const int arow_base = bm * 256;
    const int brow_base = bn * 256;

    // staging precompute: 4 loads/thread/K-tile (A0,A1,B0,B1), slot = i*512+tid,
    // LDS byte = slot*16 (linear; wave-uniform base + lane*16 holds), global
    // k-offset pre-swizzled: k = (slot%4 ^ ((row>>1)&3)) * 8 shorts.
    const unsigned short* gA[2];
    const unsigned short* gB[2];
    int ldsA[2], ldsB[2];
    #pragma unroll
    for (int i = 0; i < 2; i++) {
        const int s   = i * 512 + tid;            // 0..1023
        const int row = s >> 2;                   // 0..255
        const int sc  = s & 3;
        const int kof = (sc ^ ((row >> 1) & 3)) << 3;
        gA[i] = A + (size_t)(arow_base + row) * K_DIM + kof;
        int br = brow_base + row; if (br > N_DIM - 1) br = N_DIM - 1;
        gB[i] = B + (size_t)br * K_DIM + kof;
        ldsA[i] = s * 16;
        ldsB[i] = 16384 + s * 16;
    }

    #define STAGE_A(t2, nbb)                                                  \
        do {                                                                  \
            async_ld16(gA[0] + (size_t)(t2) * 32, (char*)smem + (nbb) + ldsA[0]); \
            async_ld16(gA[1] + (size_t)(t2) * 32, (char*)smem + (nbb) + ldsA[1]); \
        } while (0)
    #define STAGE_B(t2, nbb)                                                  \
        do {                                                                  \
            async_ld16(gB[0] + (size_t)(t2) * 32, (char*)smem + (nbb) + ldsB[0]); \
            async_ld16(gB[1] + (size_t)(t2) * 32, (char*)smem + (nbb) + ldsB[1]); \
        } while (0)

    f32x4 acc[8][4];
    #pragma unroll
    for (int i = 0; i < 8; i++)
        #pragma unroll
        for (int j = 0; j < 4; j++) {
            f32x4 z = {0.f, 0.f, 0.f, 0.f};
            acc[i][j] = z;
        }

    // ds_read bases (bytes within a buffer); frag (mh,i): +mh*4096 + i*1024
    const int aBase = (wm * 128 + mlane) * 64 + qx;
    const int bBase = 16384 + (wn * 64 + mlane) * 64 + qx;

    // prologue: stage tiles 0,1,2 into bufs 0,1,2; vmcnt(8) -> tile 0 landed,
    // tiles 1,2 in flight
    STAGE_A(0, 0);     STAGE_B(0, 0);
    STAGE_A(1, 32768); STAGE_B(1, 32768);
    STAGE_A(2, 65536); STAGE_B(2, 65536);
    WAITVM8();
    BAR();

    for (int t = 0; t < NT; ++t) {
        const int bb = (t & 3) * 32768;
        const int nb = ((t + 3) & 3) * 32768;     // buffer of tile t+3
        const char* base = (const char*)smem + bb;
        bf16x8 af[4], bfv[4];

        // ---- region A: mh=0 frags + all B frags; stage A of tile t+3 ----
        #pragma unroll
        for (int i = 0; i < 4; i++) {
            af[i]  = *(const bf16x8*)(base + aBase + i * 1024);
            bfv[i] = *(const bf16x8*)(base + bBase + i * 1024);
        }
        if (t + 3 < NT) STAGE_A(t + 3, nb);
        __builtin_amdgcn_s_setprio(1);
        #pragma unroll
        for (int i = 0; i < 4; i++)
            #pragma unroll
            for (int j = 0; j < 4; j++)
                acc[i][j] = __builtin_amdgcn_mfma_f32_16x16x32_bf16(
                    af[i], bfv[j], acc[i][j], 0, 0, 0);
        __builtin_amdgcn_s_setprio(0);
        BAR();   // mid-tile align (scheduling only)

        // ---- region B: mh=1 frags (B reused); stage B of tile t+3 ----
        #pragma unroll
        for (int i = 0; i < 4; i++)
            af[i] = *(const bf16x8*)(base + aBase + 4096 + i * 1024);
        if (t + 3 < NT) STAGE_B(t + 3, nb);
        __builtin_amdgcn_s_setprio(1);
        #pragma unroll
        for (int i = 0; i < 4; i++)
            #pragma unroll
            for (int j = 0; j < 4; j++)
                acc[4 + i][j] = __builtin_amdgcn_mfma_f32_16x16x32_bf16(
                    af[i], bfv[j], acc[4 + i][j], 0, 0, 0);
        __builtin_amdgcn_s_setprio(0);

        // boundary: tile t+1 must be resident for next iteration's reads.
        // In flight: tiles t+2 and t+3 (4 loads each) -> counted vmcnt(8).
        if (t < NT - 1) {
            if (t < NT - 3)      { WAITVM8(); }
            else if (t == NT - 3){ WAITVM4(); }
            else                 { WAITVM0(); }
        }
        BAR();   // boundary: all waves' staging of t+1 complete
    }
    #undef STAGE_A
    #undef STAGE_B

    // epilogue: fold norms, transpose 16x64 chunks through LDS, NT f32x4
    // stores (256B contiguous per row segment). Per-wave scratch 16 x stride-68.
    // W occupies bytes 0..34.8KB (buf0 + head of buf1): last readers of those
    // buffers finished before the preceding boundary barriers -- no hazard.
    float* W = (float*)smem + wave * 1088;        // 8 waves x 1088 f32 = 34.8 KB
    const int rbase0 = arow_base + wm * 128;
    const int cbase  = brow_base + wn * 64 + mlane;
    const int rb_col4 = mlane * 4;
    const int gcol4  = brow_base + wn * 64 + rb_col4;
    const bool colok = gcol4 < N_DIM;             // 4-aligned, N%4==0 -> +3 safe

    #pragma unroll
    for (int i = 0; i < 8; i++) {
        float frow[4];
        #pragma unroll
        for (int r = 0; r < 4; r++)
            frow[r] = -0.5f * fsq[rbase0 + i * 16 + quad * 4 + r];
        #pragma unroll
        for (int j = 0; j < 4; j++) {
            int col = cbase + j * 16;
            float cs = -0.5f * csq[col < N_DIM ? col : (N_DIM - 1)];
            #pragma unroll
            for (int r = 0; r < 4; r++)
                W[(quad * 4 + r) * 68 + j * 16 + mlane] = acc[i][j][r] + frow[r] + cs;
        }
        WAITLGKM();  // writes visible to own-wave reads
        #pragma unroll
        for (int s = 0; s < 4; s++) {
            int rl = s * 4 + quad;
            f32x4 v = *(const f32x4*)&W[rl * 68 + rb_col4];
            if (colok) {
                int grow = rbase0 + i * 16 + rl;
                __builtin_nontemporal_store(v, (f32x4*)&out[(size_t)grow * N_DIM + gcol4]);
            }
        }
        WAITLGKM();  // reads done before next i overwrites W
    }
}

extern "C" void kernel_launch(void* const* d_in, const int* in_sizes, int n_in,
                              void* d_out, int out_size, void* d_ws, size_t ws_size,
                              hipStream_t stream) {
    const float* feat = (const float*)d_in[0];   // [4096,1024]
    const float* cent = (const float*)d_in[1];   // [10000,1024]
    float* out = (float*)d_out;                  // [4096,10000]

    char* ws = (char*)d_ws;
    unsigned short* featbf = (unsigned short*)ws;                         // 8,388,608 B
    unsigned short* centbf = (unsigned short*)(ws + 8388608);             // 20,480,000 B
    float* fsq = (float*)(ws + 8388608 + 20480000);                       // 16,384 B
    float* csq = (float*)(ws + 8388608 + 20480000 + 16384);               // 40,000 B

    prep_rows<<<1024, 256, 0, stream>>>(feat, cent, featbf, centbf, fsq, csq);

    gemm_bt<<<GM * GN, 512, 0, stream>>>(featbf, centbf, fsq, csq, out);
}